// Round 2
// baseline (23.822 us; speedup 1.0000x reference)
//
#include <hip/hip_runtime.h>

// Problem constants (from reference): x[B,S,H], W*[H,H], b*[H], out[B,H]
#define BB 32
#define SS 1024
#define HH 256

// ---------------------------------------------------------------------------
// Math note: reference softmaxes over the QUERY axis (axis=1), so
// sum_q attn[b,q,k] == 1 for every (b,k). Then sum_q context = sum_k v.
// Hence out[b,h] = sum_h' Wv[h,h'] * (sum_s x[b,s,h']) + S * bv[h], exactly.
// Only x needs to be read (32 MB); Wq/bq/Wk/bk are provably unused.
// ---------------------------------------------------------------------------

// Kernel A: partial column sums of x over S.
// grid = BB*SPLITS blocks, 256 threads. partials layout: [BB][SPLITS][HH] f32.
// SPLITS=64 -> 2048 blocks = 8 blocks/CU = 32 waves/CU (full occupancy).
template <int SPLITS>
__global__ __launch_bounds__(256) void xsum_partial_kernel(
    const float* __restrict__ x, float* __restrict__ partials) {
    constexpr int ROWS = SS / SPLITS;
    const int blk   = blockIdx.x;
    const int b     = blk / SPLITS;
    const int split = blk % SPLITS;
    const int tid   = threadIdx.x;
    const int h4    = tid & 63;   // float4 column group: 64 groups cover 256 floats
    const int srow  = tid >> 6;   // 0..3 row phase

    const float4* xb = reinterpret_cast<const float4*>(
        x + (size_t)b * SS * HH + (size_t)split * ROWS * HH);

    float4 acc = make_float4(0.f, 0.f, 0.f, 0.f);
    #pragma unroll
    for (int r = srow; r < ROWS; r += 4) {
        float4 v = xb[(size_t)r * (HH / 4) + h4];
        acc.x += v.x; acc.y += v.y; acc.z += v.z; acc.w += v.w;
    }

    __shared__ float4 lds[256];
    lds[tid] = acc;
    __syncthreads();
    if (tid < 64) {
        float4 a0 = lds[tid];
        float4 a1 = lds[tid + 64];
        float4 a2 = lds[tid + 128];
        float4 a3 = lds[tid + 192];
        float4 r;
        r.x = (a0.x + a1.x) + (a2.x + a3.x);
        r.y = (a0.y + a1.y) + (a2.y + a3.y);
        r.z = (a0.z + a1.z) + (a2.z + a3.z);
        r.w = (a0.w + a1.w) + (a2.w + a3.w);
        reinterpret_cast<float4*>(
            partials + ((size_t)b * SPLITS + split) * HH)[h4] = r;
    }
}

// Kernel B: reduce partials -> Xsum[b,:] in LDS (float4, 4-phase), then
// out[b,h] = dot(Wv[h,:], Xsum[b,:]) + S*bv[h]. grid = BB blocks, 256 thr.
template <int SPLITS>
__global__ __launch_bounds__(256) void out_kernel(
    const float* __restrict__ partials, const float* __restrict__ Wv,
    const float* __restrict__ bv, float* __restrict__ out) {
    const int b   = blockIdx.x;
    const int tid = threadIdx.x;
    const int h4  = tid & 63;   // float4 column group
    const int ph  = tid >> 6;   // 0..3 split phase

    const float4* pb = reinterpret_cast<const float4*>(
        partials + (size_t)b * SPLITS * HH);

    float4 acc4 = make_float4(0.f, 0.f, 0.f, 0.f);
    #pragma unroll
    for (int c = ph; c < SPLITS; c += 4) {
        float4 v = pb[(size_t)c * (HH / 4) + h4];
        acc4.x += v.x; acc4.y += v.y; acc4.z += v.z; acc4.w += v.w;
    }

    __shared__ float4 lds[256];
    __shared__ float xsum[HH];
    lds[tid] = acc4;
    __syncthreads();
    if (tid < 64) {
        float4 a0 = lds[tid];
        float4 a1 = lds[tid + 64];
        float4 a2 = lds[tid + 128];
        float4 a3 = lds[tid + 192];
        float4 r;
        r.x = (a0.x + a1.x) + (a2.x + a3.x);
        r.y = (a0.y + a1.y) + (a2.y + a3.y);
        r.z = (a0.z + a1.z) + (a2.z + a3.z);
        r.w = (a0.w + a1.w) + (a2.w + a3.w);
        reinterpret_cast<float4*>(xsum)[tid] = r;
    }
    __syncthreads();

    const int h = tid;
    const float4* wrow = reinterpret_cast<const float4*>(Wv + (size_t)h * HH);
    const float4* xs   = reinterpret_cast<const float4*>(xsum);
    float acc = (float)SS * bv[h];
    #pragma unroll 8
    for (int i = 0; i < HH / 4; ++i) {
        float4 w  = wrow[i];
        float4 xv = xs[i];
        acc += w.x * xv.x + w.y * xv.y + w.z * xv.z + w.w * xv.w;
    }
    out[(size_t)b * HH + h] = acc;
}

extern "C" void kernel_launch(void* const* d_in, const int* in_sizes, int n_in,
                              void* d_out, int out_size, void* d_ws, size_t ws_size,
                              hipStream_t stream) {
    // setup_inputs order: x, Wq, bq, Wk, bk, Wv, bv
    const float* x  = (const float*)d_in[0];
    const float* Wv = (const float*)d_in[5];
    const float* bv = (const float*)d_in[6];
    float* out = (float*)d_out;
    float* partials = (float*)d_ws;

    // SPLITS=64 needs 32*64*256*4 = 2 MB of workspace; fall back if tight.
    if (ws_size >= (size_t)BB * 64 * HH * sizeof(float)) {
        xsum_partial_kernel<64><<<BB * 64, 256, 0, stream>>>(x, partials);
        out_kernel<64><<<BB, 256, 0, stream>>>(partials, Wv, bv, out);
    } else {
        xsum_partial_kernel<16><<<BB * 16, 256, 0, stream>>>(x, partials);
        out_kernel<16><<<BB, 256, 0, stream>>>(partials, Wv, bv, out);
    }
}